// Round 12
// baseline (83.534 us; speedup 1.0000x reference)
//
#include <hip/hip_runtime.h>
#include <hip/hip_bf16.h>

#define N_NODES 65536
#define N_EDGES (N_NODES * 7)
#define NSEG    (N_NODES * 7)          // 458752
#define CAP     12
#define ZROW    65536                  // index of the all-zero row in xb

typedef short short8 __attribute__((ext_vector_type(8)));
typedef float f32x4  __attribute__((ext_vector_type(4)));

// f32 -> bf16 via hardware cvt (compiler emits v_cvt_pk_bf16_f32 for pairs)
__device__ __forceinline__ unsigned short f2bf(float f) {
    return __builtin_bit_cast(unsigned short, (__bf16)f);
}
__device__ __forceinline__ unsigned pack2(float lo, float hi) {
    return (unsigned)f2bf(lo) | ((unsigned)f2bf(hi) << 16);
}
// bf16 pair unpack from dword
__device__ __forceinline__ float bflo(unsigned d) { return __uint_as_float(d << 16); }
__device__ __forceinline__ float bfhi(unsigned d) { return __uint_as_float(d & 0xffff0000u); }

// ---------------- fused prep: edge scatter + x->bf16 + W->B-frag ----------------
// seg32[seg] = cnt(7b at bit 0) | typecount_u(5b at bit 7+5u). Pre-zeroed by memset.
__global__ __launch_bounds__(256) void k_big(const float* __restrict__ x,
                                             const int* __restrict__ eidx,
                                             const int* __restrict__ etype,
                                             const int* __restrict__ ntype,
                                             const float* __restrict__ W,
                                             unsigned short* __restrict__ xb,
                                             unsigned short* __restrict__ wb,
                                             unsigned* __restrict__ seg32,
                                             unsigned short* __restrict__ scol) {
    int i = blockIdx.x * 256 + threadIdx.x;     // grid 4096*256 = 1048576

    // edge scatter (issue first: its random loads overlap the streaming below)
    if (i < N_EDGES) {
        int t = etype[i];
        if (t < 6) {                    // type-6 slot overwritten by self-loop
            int r = eidx[i];
            int c = eidx[N_EDGES + i];
            int u = ntype[c];
            unsigned seg = (unsigned)r * 7u + (unsigned)t;
            unsigned inc = 1u | (1u << (7 + 5 * u));
            unsigned old = atomicAdd(&seg32[seg], inc);
            unsigned slot = old & 0x7fu;
            if (slot < CAP) scol[seg * CAP + slot] = (unsigned short)c;
        }
    }

    // x -> bf16 rows
    {
        int row = i >> 4, mm = i & 15;
        const f32x4* p = reinterpret_cast<const f32x4*>(x + (size_t)row * 128 + mm * 8);
        f32x4 v0 = p[0], v1 = p[1];
        uint4 w;
        w.x = pack2(v0[0], v0[1]); w.y = pack2(v0[2], v0[3]);
        w.z = pack2(v1[0], v1[1]); w.w = pack2(v1[2], v1[3]);
        reinterpret_cast<uint4*>(xb)[i] = w;
    }

    // zero row (gather fallback target)
    if (i < 16) reinterpret_cast<uint4*>(xb + (size_t)ZROW * 128)[i] = (uint4){0u, 0u, 0u, 0u};

    // W -> bf16 B-fragment order
    if (i < 143360) {
        int j    = i & 7;
        int lane = (i >> 3) & 63;
        int cb   = (i >> 9) & 7;
        int tkc  = i >> 12;
        int kc   = tkc % 5;
        int t    = tkc / 5;
        int k = kc * 32 + ((lane >> 4) << 3) + j;
        int c = cb * 16 + (lane & 15);
        float v = (k < 133) ? W[(t * 133 + k) * 128 + c] : 0.0f;
        wb[i] = f2bf(v);
    }
}

// ---------------- main fused kernel ----------------
// M=64 rows/block, 512 threads (8 threads/row x 16 channels). 3-tile sA
// (64.5 KB -> 2 blocks/CU). Wave mapping (1,8): wave = one cb, reads all 4
// 16-row strips -> B-L2 halved vs M=32. A-tile XOR-swizzled (T2): slot s of
// row r stored at s ^ (((r>>3)&1)<<2), killing the (l,l+8) same-bank pairs
// (row stride 336B = 0 mod 128B). 3 phases / 5 barriers (R11 schedule).
// No gather regs live across marathons (R8); VGPR cap 128 (R11 spill fix).
__global__ __launch_bounds__(512, 4) void k_main(const unsigned short* __restrict__ xb,
                                                 const int* __restrict__ ntype,
                                                 const unsigned* __restrict__ seg32,
                                                 const unsigned short* __restrict__ scol,
                                                 const unsigned short* __restrict__ wb,
                                                 float* __restrict__ out) {
    __shared__ unsigned short sA[3 * 64 * 168];   // 64512 B

    const int tid  = threadIdx.x;
    const int lane = tid & 63;
    const int wid  = tid >> 6;
    const int n0   = blockIdx.x * 64;
    const int r    = tid >> 3;      // row 0..63
    const int m    = tid & 7;       // 16-channel chunk (shorts m*16..m*16+15)
    const int n    = n0 + r;
    const int wswz = ((r >> 3) & 1) << 5;   // write-side swizzle (shorts)

    // zero slots 17..19 (shorts 136..159) of each of the 192 rows - never rewritten
    if (tid < 192) {
        uint4 z = {0u, 0u, 0u, 0u};
        *reinterpret_cast<uint4*>(sA + tid * 168 + 136) = z;
        *reinterpret_cast<uint4*>(sA + tid * 168 + 144) = z;
        *reinterpret_cast<uint4*>(sA + tid * 168 + 152) = z;
    }

    // per-type packed counters + first-4 edge cols (broadcast within 8-lane group)
    unsigned sv[6], c_t[6];
    uint2 q2[6];
    #pragma unroll
    for (int t = 0; t < 6; ++t) {
        sv[t]  = seg32[n * 7 + t];
        c_t[t] = sv[t] & 0x7fu;
        q2[t]  = *reinterpret_cast<const uint2*>(scol + ((size_t)n * 7 + t) * CAP);
    }
    const int ntS = ntype[n];

    // add one neighbor row's 16 channels into f[16]
    auto addrow = [&](float* f, unsigned col) {
        const short8* p = reinterpret_cast<const short8*>(xb + (size_t)col * 128 + m * 16);
        short8 v0 = p[0], v1 = p[1];
        uint4 u0 = *reinterpret_cast<const uint4*>(&v0);
        uint4 u1 = *reinterpret_cast<const uint4*>(&v1);
        f[0] += bflo(u0.x); f[1] += bfhi(u0.x); f[2]  += bflo(u0.y); f[3]  += bfhi(u0.y);
        f[4] += bflo(u0.z); f[5] += bfhi(u0.z); f[6]  += bflo(u0.w); f[7]  += bfhi(u0.w);
        f[8] += bflo(u1.x); f[9] += bfhi(u1.x); f[10] += bflo(u1.y); f[11] += bfhi(u1.y);
        f[12]+= bflo(u1.z); f[13]+= bfhi(u1.z); f[14] += bflo(u1.w); f[15] += bfhi(u1.w);
    };

    // ---- tile builder: one (row,t) segment, this thread's 16 channels ----
    auto build_tile = [&](int t, int tile) {
        const unsigned cntv = c_t[t];
        const float inv = (cntv > 1u) ? __builtin_amdgcn_rcpf((float)cntv) : 1.0f;
        unsigned cA = (cntv >= 1u) ? (q2[t].x & 0xffffu) : (unsigned)ZROW;
        unsigned cB = (cntv >= 2u) ? (q2[t].x >> 16)     : (unsigned)ZROW;
        const short8* pA = reinterpret_cast<const short8*>(xb + (size_t)cA * 128 + m * 16);
        const short8* pB = reinterpret_cast<const short8*>(xb + (size_t)cB * 128 + m * 16);
        short8 a0 = pA[0], a1 = pA[1];
        short8 b0 = pB[0], b1 = pB[1];
        uint4 w0, w1;
        if (cntv <= 1u) {
            w0 = *reinterpret_cast<const uint4*>(&a0);   // cnt=0 -> zeros; cnt=1 -> exact
            w1 = *reinterpret_cast<const uint4*>(&a1);
        } else {
            uint4 ua0 = *reinterpret_cast<const uint4*>(&a0);
            uint4 ua1 = *reinterpret_cast<const uint4*>(&a1);
            uint4 ub0 = *reinterpret_cast<const uint4*>(&b0);
            uint4 ub1 = *reinterpret_cast<const uint4*>(&b1);
            float f[16];
            f[0] = bflo(ua0.x)+bflo(ub0.x); f[1] = bfhi(ua0.x)+bfhi(ub0.x);
            f[2] = bflo(ua0.y)+bflo(ub0.y); f[3] = bfhi(ua0.y)+bfhi(ub0.y);
            f[4] = bflo(ua0.z)+bflo(ub0.z); f[5] = bfhi(ua0.z)+bfhi(ub0.z);
            f[6] = bflo(ua0.w)+bflo(ub0.w); f[7] = bfhi(ua0.w)+bfhi(ub0.w);
            f[8] = bflo(ua1.x)+bflo(ub1.x); f[9] = bfhi(ua1.x)+bfhi(ub1.x);
            f[10]= bflo(ua1.y)+bflo(ub1.y); f[11]= bfhi(ua1.y)+bfhi(ub1.y);
            f[12]= bflo(ua1.z)+bflo(ub1.z); f[13]= bfhi(ua1.z)+bfhi(ub1.z);
            f[14]= bflo(ua1.w)+bflo(ub1.w); f[15]= bfhi(ua1.w)+bfhi(ub1.w);
            if (cntv >= 3u) {               // rare tail (~8% of segments)
                const unsigned ce = (cntv < (unsigned)CAP) ? cntv : (unsigned)CAP;
                addrow(f, q2[t].y & 0xffffu);
                if (ce >= 4u) {
                    addrow(f, q2[t].y >> 16);
                    const size_t segbase = ((size_t)n * 7 + t) * CAP;
                    for (unsigned e = 4; e < ce; ++e)
                        addrow(f, (unsigned)scol[segbase + e]);
                }
            }
            w0.x = pack2(f[0]*inv,  f[1]*inv);  w0.y = pack2(f[2]*inv,  f[3]*inv);
            w0.z = pack2(f[4]*inv,  f[5]*inv);  w0.w = pack2(f[6]*inv,  f[7]*inv);
            w1.x = pack2(f[8]*inv,  f[9]*inv);  w1.y = pack2(f[10]*inv, f[11]*inv);
            w1.z = pack2(f[12]*inv, f[13]*inv); w1.w = pack2(f[14]*inv, f[15]*inv);
        }
        const int base = (tile * 64 + r) * 168;
        const int o = (m * 16) ^ wswz;          // swizzled slot pair (stays < 128)
        *reinterpret_cast<uint4*>(sA + base + o)     = w0;
        *reinterpret_cast<uint4*>(sA + base + o + 8) = w1;
        if (m == 0) {
            float g0 = (float)((sv[t] >> 7)  & 31u) * inv;
            float g1 = (float)((sv[t] >> 12) & 31u) * inv;
            float g2 = (float)((sv[t] >> 17) & 31u) * inv;
            float g3 = (float)((sv[t] >> 22) & 31u) * inv;
            float g4 = (float)((sv[t] >> 27) & 31u) * inv;
            uint4 wo;
            wo.x = pack2(g0, g1); wo.y = pack2(g2, g3);
            wo.z = pack2(g4, 0.f); wo.w = 0u;
            *reinterpret_cast<uint4*>(sA + base + 128) = wo;   // slot 16 unswizzled
        }
    };

    auto build_self = [&](int tile) {
        const short8* p = reinterpret_cast<const short8*>(xb + (size_t)n * 128 + m * 16);
        short8 s0 = p[0], s1 = p[1];
        const int base = (tile * 64 + r) * 168;
        const int o = (m * 16) ^ wswz;
        *reinterpret_cast<uint4*>(sA + base + o)     = *reinterpret_cast<const uint4*>(&s0);
        *reinterpret_cast<uint4*>(sA + base + o + 8) = *reinterpret_cast<const uint4*>(&s1);
        if (m == 0) {
            uint4 wo;
            wo.x = pack2((float)(ntS == 0), (float)(ntS == 1));
            wo.y = pack2((float)(ntS == 2), (float)(ntS == 3));
            wo.z = pack2((float)(ntS == 4), 0.f);
            wo.w = 0u;
            *reinterpret_cast<uint4*>(sA + base + 128) = wo;
        }
    };

    // marathon lane constants
    const int arl  = lane & 15;
    const int g8   = (lane >> 4) << 3;
    const int rswz = ((lane >> 3) & 1) << 5;   // read-side swizzle (= row bit3)
    f32x4 acc[4];
    #pragma unroll
    for (int st = 0; st < 4; ++st) acc[st] = (f32x4){0.f, 0.f, 0.f, 0.f};

    auto marathon = [&](int slot, int bt) {
        short8 bv[5];
        #pragma unroll
        for (int kc = 0; kc < 5; ++kc)
            bv[kc] = *reinterpret_cast<const short8*>(
                wb + ((((bt * 5 + kc) * 8 + wid) << 6) + lane) * 8);
        #pragma unroll
        for (int kc = 0; kc < 5; ++kc) {
            const int off = (kc < 4) ? ((kc * 32 + g8) ^ rswz) : (128 + g8);
            #pragma unroll
            for (int st = 0; st < 4; ++st) {
                short8 av = *reinterpret_cast<const short8*>(
                    sA + (slot * 64 + st * 16 + arl) * 168 + off);
                acc[st] = __builtin_amdgcn_mfma_f32_16x16x32_bf16(av, bv[kc], acc[st], 0, 0, 0);
            }
        }
    };

    // ---- phase 1: {t0,t1,self} ----
    build_tile(0, 0);
    build_tile(1, 1);
    build_self(2);
    __syncthreads();
    marathon(0, 0); marathon(1, 1); marathon(2, 6);
    __syncthreads();

    // ---- phase 2: {t2,t3} ----
    build_tile(2, 0);
    build_tile(3, 1);
    __syncthreads();
    marathon(0, 2); marathon(1, 3);
    __syncthreads();

    // ---- phase 3: {t4,t5} ----
    build_tile(4, 0);
    build_tile(5, 1);
    __syncthreads();
    marathon(0, 4); marathon(1, 5);

    // epilogue: C/D layout col = lane&15, row = (lane>>4)*4 + reg
    const int ocol = (wid << 4) + (lane & 15);
    const int ro   = ((lane >> 4) << 2);
    #pragma unroll
    for (int st = 0; st < 4; ++st) {
        #pragma unroll
        for (int rr = 0; rr < 4; ++rr) {
            out[(size_t)(n0 + st * 16 + ro + rr) * 128 + ocol] = acc[st][rr];
        }
    }
}

// ---------------- launch ----------------

extern "C" void kernel_launch(void* const* d_in, const int* in_sizes, int n_in,
                              void* d_out, int out_size, void* d_ws, size_t ws_size,
                              hipStream_t stream) {
    const float* x     = (const float*)d_in[0];
    const int*   eidx  = (const int*)d_in[1];
    const int*   etype = (const int*)d_in[2];
    const int*   ntype = (const int*)d_in[3];
    const float* W     = (const float*)d_in[4];
    float* out = (float*)d_out;

    // ws: xb (65537 rows) 16777472 | wb 286720 | seg32 1835008 | scol 11010048
    unsigned short* xb    = (unsigned short*)d_ws;
    unsigned short* wb    = (unsigned short*)((char*)d_ws + 16777472);
    unsigned*       seg32 = (unsigned*)((char*)d_ws + 17064192);
    unsigned short* scol  = (unsigned short*)((char*)d_ws + 18899200);

    hipMemsetAsync(seg32, 0, NSEG * sizeof(unsigned), stream);
    k_big <<<4096,         256, 0, stream>>>(x, eidx, etype, ntype, W, xb, wb, seg32, scol);
    k_main<<<N_NODES / 64, 512, 0, stream>>>(xb, ntype, seg32, scol, wb, out);
}